// Round 8
// baseline (15309.596 us; speedup 1.0000x reference)
//
#include <hip/hip_runtime.h>

typedef float f32x2 __attribute__((ext_vector_type(2)));

// ---------------------------------------------------------------------------
// VOP3P packed f32 (2 f32 ops per instruction per lane). Same IEEE f32 RN
// rounding per element as the scalar ops they replace.
// ---------------------------------------------------------------------------
__device__ __forceinline__ f32x2 pk_add(f32x2 a, f32x2 b) {
    f32x2 d; asm("v_pk_add_f32 %0, %1, %2" : "=v"(d) : "v"(a), "v"(b)); return d;
}
__device__ __forceinline__ f32x2 pk_mul(f32x2 a, f32x2 b) {
    f32x2 d; asm("v_pk_mul_f32 %0, %1, %2" : "=v"(d) : "v"(a), "v"(b)); return d;
}
__device__ __forceinline__ f32x2 pk_fma(f32x2 a, f32x2 b, f32x2 c) {
    f32x2 d; asm("v_pk_fma_f32 %0, %1, %2, %3" : "=v"(d) : "v"(a), "v"(b), "v"(c)); return d;
}

// ---------------------------------------------------------------------------
// Strict f64 squared distance matching numpy float64:
//   d = ((dx*dx + dy*dy) + dz*dz), every op individually rounded, no FMA.
// ---------------------------------------------------------------------------
__device__ __forceinline__ double dist2d(float x, float y, float z,
                                         double px, double py, double pz) {
    double dx = __dsub_rn((double)x, px);
    double dy = __dsub_rn((double)y, py);
    double dz = __dsub_rn((double)z, pz);
    double a  = __dmul_rn(dx, dx);
    double b  = __dmul_rn(dy, dy);
    double c  = __dmul_rn(dz, dz);
    return __dadd_rn(__dadd_rn(a, b), c);
}

// DPP move; lanes with invalid source keep their own value (bound_ctrl=false).
template <int CTRL>
__device__ __forceinline__ unsigned dpp_u32_keep(unsigned v) {
    return (unsigned)__builtin_amdgcn_update_dpp((int)v, (int)v, CTRL, 0xF, 0xF, false);
}

// After this, lane 63 holds umax over all 64 lanes.
__device__ __forceinline__ unsigned wave_umax64(unsigned v) {
    v = max(v, dpp_u32_keep<0x111>(v));  // row_shr:1
    v = max(v, dpp_u32_keep<0x112>(v));  // row_shr:2
    v = max(v, dpp_u32_keep<0x114>(v));  // row_shr:4
    v = max(v, dpp_u32_keep<0x118>(v));  // row_shr:8
    v = max(v, dpp_u32_keep<0x142>(v));  // row_bcast:15
    v = max(v, dpp_u32_keep<0x143>(v));  // row_bcast:31
    return v;
}

__device__ __forceinline__ float readlane_f32(float v, int l) {
    return __int_as_float(__builtin_amdgcn_readlane(__float_as_int(v), l));
}

// Among lanes in mask (nonempty): all hold equal hi; pick max lo, then min idx.
// Fast path when unique. Mask strictly shrinks -> terminates (<=64 iters).
__device__ __forceinline__ int pick_lane(unsigned long long m, unsigned lo, int idx) {
    if (__popcll(m) == 1) return __ffsll(m) - 1;
    unsigned bl = 0; int bidx = 0x7FFFFFFF; int ml = -1;
    unsigned long long t = m;
    while (t) {
        int l = __ffsll(t) - 1;
        unsigned lol = (unsigned)__builtin_amdgcn_readlane((int)lo, l);
        int      il  = __builtin_amdgcn_readlane(idx, l);
        if (ml < 0 || lol > bl || (lol == bl && il < bidx)) { bl = lol; bidx = il; ml = l; }
        t &= t - 1;
    }
    return ml;
}

// ---------------------------------------------------------------------------
// FPS, TWO BATCHES PER BLOCK. NT=1024 = 16 waves; waves 0..GW-1 run batch
// 2*blockIdx+0, waves GW..2GW-1 run batch 2*blockIdx+1. Each group is the
// exact single-batch machine (R4 champion state machine, R7-verified
// per-group shape: 512 threads, PPT=16, 8 partials). Only the BARRIER is
// shared between groups (strictly more conservative than group-local sync).
// Rationale (measured R2/R4/R6/R7): wall = ~0.6*per-SIMD-issue + latency
// term that needs co-resident waves to hide. Per SIMD this kernel holds
// 2 A-waves + 2 B-waves with INDEPENDENT dependence chains: when one
// group's reduce/update chain stalls, the other group issues. Barrier cost
// amortized over 2 batches; phase-2 reduce is over 8 partials (3 DPP steps).
//
// Exactness: md is f64, bit-matching numpy float64 (dist2d). md >= 0, and for
// non-negative IEEE doubles value order == integer order of (hi32, lo32), so
// all max machinery runs on u32 hi-words (v_max_u32 DPP); exact hi-ties fall
// to pick_lane resolving (lo desc, idx asc). argmax tie-break = min index.
//
// Issue-count machinery (the R4 champion state machine, group-local):
//   - cached wave winner: the 64-lane DPP reduce + ballot + readlane extract
//     runs ONLY after a rescan (reduce_winner); steady-state phase 1 is just
//     two masked LDS writes, skipped when the parity buffer is current
//     (pub0/pub1). Safe: the selected point always fires its own wave's
//     rescan (its own slot takes d=0 < md with bj==j).
//   - rescan-skip: updates only DECREASE md; keep-first invariant => all
//     j < bj have md[j] < bv strictly, so no new smaller-index tie can form.
//     Stale iff slot bj itself took d < old; gate on __any.
//   - phase-2 LDS reads exec-masked to lane<GW; DPP row_shr never crosses
//     16-lane rows so higher lanes never feed the reduce.
//   - screen: v_pk_* packed f32, per-element rounding identical to scalar;
//     margin 1.000004 >> 3-ulp fma error => screened-out slots provably
//     unchanged; md stays bit-exact.
//   - ZERO global memory ops in the serial loop (LDS history, bulk dump).
//
// Hang/poison safety: barriers at top-level with block-uniform trip count
// (npoints identical for both groups); pick_lane masks strictly shrink;
// NaN/garbage cannot hang (integer compares; NaN f64/f32 compares false);
// all in-loop indexing is LDS with construction-bounded indices; per-lane
// arrays use compile-time indices only.
//
// Only level-1 FPS runs. FPS is nested: FPS on the ordered output of a
// previous FPS selects indices 0,1,2,... bit-exactly (subset-max argument;
// selected points have running dist 0; argmax tie-break = first occurrence).
// So idx2/3/4 are arange() -> identity gathers in the MLP levels.
// ---------------------------------------------------------------------------
template <int PPT, int NT, int GW>   // GW = waves per batch-group
__global__ __launch_bounds__(NT, 4) void fps_kernel(
    const float* __restrict__ pts,  // [B][n_in][stride], xyz at channels 0..2
    int stride, int npoints,
    int* __restrict__ idx_out)      // [B][npoints]
{
    constexpr int NWAVES = NT / 64;          // 16
    constexpr int NGRP   = NWAVES / GW;      // 2
    constexpr int GT     = GW * 64;          // threads per group (512)
    constexpr int N_IN   = PPT * GT;         // points per batch (8192)
    constexpr int NPAIR  = PPT / 2;
    constexpr int LOGGT  = (GT == 1024) ? 10 : (GT == 512) ? 9 : 8;

    const int tid  = threadIdx.x;
    const int lane = tid & 63;
    const int wv   = tid >> 6;               // 0..NWAVES-1
    const int grp  = wv / GW;                // batch group within block
    const int gwv  = wv - grp * GW;          // wave within group
    const int gtid = tid - grp * GT;         // thread within group

    const int batch = blockIdx.x * NGRP + grp;
    const float* base = pts + (size_t)batch * N_IN * stride;
    int* iout = idx_out + (size_t)batch * npoints;

    __shared__ uint2  s_pk[2][NGRP][GW];   // {hi32 of winner value, winner idx}
    __shared__ float4 s_c[2][NGRP][GW];    // {x, y, z, lo32-as-float}
    __shared__ int    s_hist[NGRP][4096];  // npoints <= 4096

    f32x2  pcx[NPAIR], pcy[NPAIR], pcz[NPAIR];
    double md[PPT];
    float  th[PPT];

#pragma unroll
    for (int k = 0; k < NPAIR; ++k) {
        int p0 = (2 * k) * GT + gtid;
        int p1 = (2 * k + 1) * GT + gtid;
        const float* r0 = base + (size_t)p0 * stride;
        const float* r1 = base + (size_t)p1 * stride;
        pcx[k] = f32x2{r0[0], r1[0]};
        pcy[k] = f32x2{r0[1], r1[1]};
        pcz[k] = f32x2{r0[2], r1[2]};
    }

    // first selected point is index 0
    float q0x = base[0], q0y = base[1], q0z = base[2];
    if (gtid == 0) s_hist[grp][0] = 0;

    // per-lane argmax state: value (f64), slot, coords. keep-first scan.
    double bv = -1.0;
    int    bj = 0;
    float  bx = 0.f, by = 0.f, bz = 0.f;
#pragma unroll
    for (int j = 0; j < PPT; ++j) {
        float x = pcx[j / 2][j & 1], y = pcy[j / 2][j & 1], z = pcz[j / 2][j & 1];
        md[j] = dist2d(x, y, z, (double)q0x, (double)q0y, (double)q0z);
        th[j] = __fmul_rn((float)md[j], 1.000004f);
        if (md[j] > bv) { bv = md[j]; bj = j; bx = x; by = y; bz = z; }
    }

    // cached wave winner (wave-uniform after reduce_winner)
    unsigned w_hi = 0, w_lo = 0;
    int      w_i  = 0;
    float    w_x = 0.f, w_y = 0.f, w_z = 0.f;
    bool pub0 = false, pub1 = false;

    auto reduce_winner = [&]() {
        unsigned hi = (unsigned)__double2hiint(bv);
        unsigned lo = (unsigned)__double2loint(bv);
        int      bi = (bj << LOGGT) + gtid;
        unsigned maxhi = (unsigned)__builtin_amdgcn_readlane((int)wave_umax64(hi), 63);
        int wl = pick_lane(__ballot(hi == maxhi), lo, bi);
        w_hi = maxhi;
        w_lo = (unsigned)__builtin_amdgcn_readlane((int)lo, wl);
        w_i  = __builtin_amdgcn_readlane(bi, wl);
        w_x  = readlane_f32(bx, wl);
        w_y  = readlane_f32(by, wl);
        w_z  = readlane_f32(bz, wl);
        pub0 = false; pub1 = false;
    };
    reduce_winner();

    for (int i = 1; i < npoints; ++i) {
        const int par = i & 1;

        // ---- phase 1: publish cached winner (skip if buffer current) ----
        bool pub = par ? pub1 : pub0;
        if (!pub) {
            if (lane == 0) {
                s_pk[par][grp][gwv] = make_uint2(w_hi, (unsigned)w_i);
                s_c[par][grp][gwv]  = make_float4(w_x, w_y, w_z, __uint_as_float(w_lo));
            }
            if (par) pub1 = true; else pub0 = true;
        }
        __syncthreads();   // shared across both groups; no vmem in-loop

        // ---- phase 2: reduce GW partials; loads masked to lane<GW ----
        unsigned phi = 0u, pidx = 0u;
        float pqx = 0.f, pqy = 0.f, pqz = 0.f, plo = 0.f;
        if (lane < GW) {
            uint2  pk = s_pk[par][grp][lane];
            float4 pc = s_c[par][grp][lane];
            phi = pk.x; pidx = pk.y;
            pqx = pc.x; pqy = pc.y; pqz = pc.z; plo = pc.w;
        }
        unsigned v2 = phi;   // lanes >= GW hold 0
        v2 = max(v2, dpp_u32_keep<0x111>(v2));
        v2 = max(v2, dpp_u32_keep<0x112>(v2));
        if constexpr (GW >= 8)  v2 = max(v2, dpp_u32_keep<0x114>(v2));
        if constexpr (GW >= 16) v2 = max(v2, dpp_u32_keep<0x118>(v2));
        unsigned ghi = (unsigned)__builtin_amdgcn_readlane((int)v2, GW - 1);
        int wl2 = pick_lane(__ballot((lane < GW) && (phi == ghi)),
                            (unsigned)__float_as_int(plo), (int)pidx);
        int best = __builtin_amdgcn_readlane((int)pidx, wl2);
        if (gtid == 0) s_hist[grp][i] = best;

        // winner coords via readlane (no dependent LDS read)
        const float qx = readlane_f32(pqx, wl2);
        const float qy = readlane_f32(pqy, wl2);
        const float qz = readlane_f32(pqz, wl2);
        const double qx64 = (double)qx, qy64 = (double)qy, qz64 = (double)qz;

        // ---- packed branchless screen -> wave-uniform fire mask ----
        const f32x2 nqx = {-qx, -qx}, nqy = {-qy, -qy}, nqz = {-qz, -qz};
        int fmask = 0;
#pragma unroll
        for (int k = 0; k < NPAIR; ++k) {
            f32x2 dx = pk_add(pcx[k], nqx);
            f32x2 dy = pk_add(pcy[k], nqy);
            f32x2 dz = pk_add(pcz[k], nqz);
            f32x2 d  = pk_fma(dx, dx, pk_fma(dy, dy, pk_mul(dz, dz)));
            fmask |= (__any(d.x < th[2 * k])     ? (1 << (2 * k))     : 0);
            fmask |= (__any(d.y < th[2 * k + 1]) ? (1 << (2 * k + 1)) : 0);
        }

        if (fmask) {
            bool need = false;
#pragma unroll
            for (int j = 0; j < PPT; ++j) {
                if (fmask & (1 << j)) {
                    float x = pcx[j / 2][j & 1], y = pcy[j / 2][j & 1], z = pcz[j / 2][j & 1];
                    double d   = dist2d(x, y, z, qx64, qy64, qz64);
                    double old = md[j];
                    // stale iff the best slot itself decreased (see proof above)
                    need = need | ((bj == j) & (d < old));
                    md[j] = fmin(old, d);
                    th[j] = __fmul_rn((float)md[j], 1.000004f);
                }
            }
            if (__any(need)) {
                bv = -1.0; bj = 0;
#pragma unroll
                for (int j = 0; j < PPT; ++j) {
                    if (md[j] > bv) {
                        bv = md[j]; bj = j;
                        bx = pcx[j / 2][j & 1]; by = pcy[j / 2][j & 1]; bz = pcz[j / 2][j & 1];
                    }
                }
                reduce_winner();
            }
        }
    }

    // coalesced bulk dump of the selected indices (group-strided)
    __syncthreads();
    for (int k = gtid; k < npoints; k += GT) iout[k] = s_hist[grp][k];
}

// ---------------------------------------------------------------------------
// Gather + 2-layer pointwise MLP + xyz/feat concat, one kernel per level.
// IDENT=true: identity gather (FPS nesting property -> idx == arange).
// ---------------------------------------------------------------------------
template <int CIN, int F, bool REPEAT, bool IDENT>
__global__ __launch_bounds__(256) void mlp_kernel(
    const float* __restrict__ pts, int stride, int n_in,
    const int* __restrict__ idx,
    const float* __restrict__ w1, const float* __restrict__ b1,
    const float* __restrict__ w2, const float* __restrict__ b2,
    float* __restrict__ out, int np)
{
    constexpr int P    = 256 / F;
    constexpr int CINS = REPEAT ? (CIN / 2) : CIN;  // stored input channels
    constexpr int LOGF = (F == 16) ? 4 : (F == 32) ? 5 : (F == 64) ? 6 : 7;

    __shared__ float xs[P][CINS];
    __shared__ float h[P][F];

    const int tid = threadIdx.x;
    const int pl  = tid >> LOGF;       // point within block
    const int c   = tid & (F - 1);     // output channel
    const int b   = blockIdx.y;
    const int pid = blockIdx.x * P + pl;

    const int id = IDENT ? pid : idx[(size_t)b * np + pid];
    const float* row = pts + ((size_t)b * n_in + id) * stride;

    if (c < CINS) xs[pl][c] = row[c];
    __syncthreads();

    float acc = b1[c];
#pragma unroll
    for (int k = 0; k < CIN; ++k) {
        const int xk = REPEAT ? (k % 3) : k;
        acc = fmaf(xs[pl][xk], w1[k * F + c], acc);
    }
    h[pl][c] = fmaxf(acc, 0.0f);
    __syncthreads();

    float acc2 = b2[c];
#pragma unroll
    for (int f = 0; f < F; ++f)
        acc2 = fmaf(h[pl][f], w2[f * F + c], acc2);

    float res = (c < 3) ? xs[pl][c] : acc2;
    out[((size_t)b * np + pid) * (size_t)F + c] = res;
}

// ---------------------------------------------------------------------------
// Launch. Only level-1 FPS is computed (2 batches per block, 4 blocks);
// levels 2-4 are identity gathers.
// ---------------------------------------------------------------------------
extern "C" void kernel_launch(void* const* d_in, const int* in_sizes, int n_in_cnt,
                              void* d_out, int out_size, void* d_ws, size_t ws_size,
                              hipStream_t stream) {
    const float* scene = (const float*)d_in[0];
    const float* w1_1 = (const float*)d_in[1];
    const float* b1_1 = (const float*)d_in[2];
    const float* w2_1 = (const float*)d_in[3];
    const float* b2_1 = (const float*)d_in[4];
    const float* w1_2 = (const float*)d_in[5];
    const float* b1_2 = (const float*)d_in[6];
    const float* w2_2 = (const float*)d_in[7];
    const float* b2_2 = (const float*)d_in[8];
    const float* w1_3 = (const float*)d_in[9];
    const float* b1_3 = (const float*)d_in[10];
    const float* w2_3 = (const float*)d_in[11];
    const float* b2_3 = (const float*)d_in[12];
    const float* w1_4 = (const float*)d_in[13];
    const float* b1_4 = (const float*)d_in[14];
    const float* w2_4 = (const float*)d_in[15];
    const float* b2_4 = (const float*)d_in[16];

    float* out  = (float*)d_out;
    float* out1 = out;                 // [8][4096][16]
    float* out2 = out + 524288;        // [8][2048][32]
    float* out3 = out + 1048576;       // [8][1024][64]
    float* out4 = out + 1572864;       // [8][512][128]

    int* idx1 = (int*)d_ws;            // 8*4096 (only level-1 indices needed)

    const int B = 8;

    // Level 1: N=8192 -> 4096, cin=6 (repeat), F=16.
    // 2 batches per block: 4 blocks x 16 waves; group = 8 waves x PPT=16.
    fps_kernel<16, 1024, 8><<<B / 2, 1024, 0, stream>>>(scene, 3, 4096, idx1);
    mlp_kernel<6, 16, true, false><<<dim3(256, B), 256, 0, stream>>>(
        scene, 3, 8192, idx1, w1_1, b1_1, w2_1, b2_1, out1, 4096);

    // Level 2: 4096 -> 2048, cin=16, F=32   (identity gather, no FPS)
    mlp_kernel<16, 32, false, true><<<dim3(256, B), 256, 0, stream>>>(
        out1, 16, 4096, nullptr, w1_2, b1_2, w2_2, b2_2, out2, 2048);

    // Level 3: 2048 -> 1024, cin=32, F=64   (identity gather, no FPS)
    mlp_kernel<32, 64, false, true><<<dim3(256, B), 256, 0, stream>>>(
        out2, 32, 2048, nullptr, w1_3, b1_3, w2_3, b2_3, out3, 1024);

    // Level 4: 1024 -> 512, cin=64, F=128   (identity gather, no FPS)
    mlp_kernel<64, 128, false, true><<<dim3(256, B), 256, 0, stream>>>(
        out3, 64, 1024, nullptr, w1_4, b1_4, w2_4, b2_4, out4, 512);
}

// Round 10
// 5929.225 us; speedup vs baseline: 2.5821x; 2.5821x over previous
//
#include <hip/hip_runtime.h>

typedef float f32x2 __attribute__((ext_vector_type(2)));

// ---------------------------------------------------------------------------
// VOP3P packed f32 (2 f32 ops per instruction per lane). Same IEEE f32 RN
// rounding per element as the scalar ops they replace.
// ---------------------------------------------------------------------------
__device__ __forceinline__ f32x2 pk_add(f32x2 a, f32x2 b) {
    f32x2 d; asm("v_pk_add_f32 %0, %1, %2" : "=v"(d) : "v"(a), "v"(b)); return d;
}
__device__ __forceinline__ f32x2 pk_mul(f32x2 a, f32x2 b) {
    f32x2 d; asm("v_pk_mul_f32 %0, %1, %2" : "=v"(d) : "v"(a), "v"(b)); return d;
}
__device__ __forceinline__ f32x2 pk_fma(f32x2 a, f32x2 b, f32x2 c) {
    f32x2 d; asm("v_pk_fma_f32 %0, %1, %2, %3" : "=v"(d) : "v"(a), "v"(b), "v"(c)); return d;
}

// ---------------------------------------------------------------------------
// Strict f64 squared distance matching numpy float64:
//   d = ((dx*dx + dy*dy) + dz*dz), every op individually rounded, no FMA.
// ---------------------------------------------------------------------------
__device__ __forceinline__ double dist2d(float x, float y, float z,
                                         double px, double py, double pz) {
    double dx = __dsub_rn((double)x, px);
    double dy = __dsub_rn((double)y, py);
    double dz = __dsub_rn((double)z, pz);
    double a  = __dmul_rn(dx, dx);
    double b  = __dmul_rn(dy, dy);
    double c  = __dmul_rn(dz, dz);
    return __dadd_rn(__dadd_rn(a, b), c);
}

// DPP move; lanes with invalid source keep their own value (bound_ctrl=false).
template <int CTRL>
__device__ __forceinline__ unsigned dpp_u32_keep(unsigned v) {
    return (unsigned)__builtin_amdgcn_update_dpp((int)v, (int)v, CTRL, 0xF, 0xF, false);
}
template <int CTRL>
__device__ __forceinline__ float dpp_f32_keep(float v) {
    int b = __builtin_amdgcn_update_dpp(__float_as_int(v), __float_as_int(v), CTRL, 0xF, 0xF, false);
    return __int_as_float(b);
}

// After these, lane 63 holds the reduction over all 64 lanes.
__device__ __forceinline__ unsigned wave_umax64(unsigned v) {
    v = max(v, dpp_u32_keep<0x111>(v));
    v = max(v, dpp_u32_keep<0x112>(v));
    v = max(v, dpp_u32_keep<0x114>(v));
    v = max(v, dpp_u32_keep<0x118>(v));
    v = max(v, dpp_u32_keep<0x142>(v));
    v = max(v, dpp_u32_keep<0x143>(v));
    return v;
}
__device__ __forceinline__ float wave_fmax64(float v) {
    v = fmaxf(v, dpp_f32_keep<0x111>(v));
    v = fmaxf(v, dpp_f32_keep<0x112>(v));
    v = fmaxf(v, dpp_f32_keep<0x114>(v));
    v = fmaxf(v, dpp_f32_keep<0x118>(v));
    v = fmaxf(v, dpp_f32_keep<0x142>(v));
    v = fmaxf(v, dpp_f32_keep<0x143>(v));
    return v;
}
__device__ __forceinline__ float wave_fmin64(float v) {
    v = fminf(v, dpp_f32_keep<0x111>(v));
    v = fminf(v, dpp_f32_keep<0x112>(v));
    v = fminf(v, dpp_f32_keep<0x114>(v));
    v = fminf(v, dpp_f32_keep<0x118>(v));
    v = fminf(v, dpp_f32_keep<0x142>(v));
    v = fminf(v, dpp_f32_keep<0x143>(v));
    return v;
}

__device__ __forceinline__ float readlane_f32(float v, int l) {
    return __int_as_float(__builtin_amdgcn_readlane(__float_as_int(v), l));
}

// Among lanes in mask (nonempty): all hold equal hi; pick max lo, then min idx.
// Fast path when unique. Mask strictly shrinks -> terminates (<=64 iters).
__device__ __forceinline__ int pick_lane(unsigned long long m, unsigned lo, int idx) {
    if (__popcll(m) == 1) return __ffsll(m) - 1;
    unsigned bl = 0; int bidx = 0x7FFFFFFF; int ml = -1;
    unsigned long long t = m;
    while (t) {
        int l = __ffsll(t) - 1;
        unsigned lol = (unsigned)__builtin_amdgcn_readlane((int)lo, l);
        int      il  = __builtin_amdgcn_readlane(idx, l);
        if (ml < 0 || lol > bl || (lol == bl && il < bidx)) { bl = lol; bidx = il; ml = l; }
        t &= t - 1;
    }
    return ml;
}

// ---------------------------------------------------------------------------
// FPS with SPATIAL OWNERSHIP + WAVE-LEVEL SKIP. One block per batch.
//
// Setup (once, ~15us): 8x8x8 counting sort of the 8192 points by cell id
// (LDS histogram + Hillis-Steele prefix + atomic scatter of the PERMUTATION);
// wave wv then owns the 512 spatially-contiguous sorted positions
// [wv*512, (wv+1)*512), gathered into registers with per-slot ORIGINAL index
// oi[j]. Wave bbox computed by DPP min/max. The permutation order (atomics)
// is non-deterministic but selection is permutation-independent: all
// tie-breaks use the global original index.
//
// Steady-state iteration (R4 champion machine + skip):
//   - cached wave winner, publish-skip parity flags, rescan-gate (stale iff
//     the best slot itself decreased: updates only DECREASE md, and a
//     decrease can never CREATE a tie at bv since d < old <= bv), phase-2
//     u32-hi DPP reduce over NWAVES partials with (lo desc, oi asc) ties.
//   - WAVE SKIP: after q is known, skip screen+update iff
//       dist2(q, wave_bbox) > tmaxw * 1.00002   (f32, conservative margin)
//     where tmaxw >= max th over the wave's points (stale-high bound: th
//     only decreases; refreshed on every rescan). Skip => provably fmask=0.
//     The selected point's wave has dist2=0 => never skips => always fires
//     its own rescan (cache-coherence argument intact).
//   - in-lane scans tie-break on oi (min original index); reduce keys = oi.
//   - screen: v_pk_* packed f32, margin 1.000004 >> 3-ulp fma error =>
//     screened-out slots provably unchanged; md stays bit-exact f64.
//   - ZERO global memory ops in the serial loop (LDS history, bulk dump).
//
// Hang/poison safety: all barriers top-level with block-uniform trip count
// (the skip 'continue' jumps to the next iteration's single barrier, so
// every wave hits exactly one barrier per iteration); scan/scatter loops
// have fixed bounds; NaN/garbage coords degrade to cell 0 and bbox garbage
// only disables skips (performance, not correctness); scatter positions are
// bounded (each thread adds exactly PPT to the histogram, so prefix ranges
// tile [0, N_IN) exactly); pick_lane masks strictly shrink; per-lane arrays
// use compile-time indices only.
//
// Only level-1 FPS runs. FPS is nested: FPS on the ordered output of a
// previous FPS selects indices 0,1,2,... bit-exactly (subset-max argument;
// selected points have running dist 0; argmax tie-break = first occurrence).
// So idx2/3/4 are arange() -> identity gathers in the MLP levels.
// ---------------------------------------------------------------------------
template <int PPT, int NT>
__global__ __launch_bounds__(NT, 2) void fps_kernel(
    const float* __restrict__ pts,  // [B][n_in][stride], xyz at channels 0..2
    int stride, int npoints,
    int* __restrict__ idx_out)      // [B][npoints]
{
    constexpr int NWAVES = NT / 64;
    constexpr int N_IN   = PPT * NT;
    constexpr int NPAIR  = PPT / 2;
    constexpr int WPTS   = N_IN / NWAVES;   // points per wave (512)

    const int batch = blockIdx.x;
    const int tid   = threadIdx.x;
    const int lane  = tid & 63;
    const int wv    = tid >> 6;

    const float* base = pts + (size_t)batch * N_IN * stride;
    int* iout = idx_out + (size_t)batch * npoints;

    __shared__ uint2  s_pk[2][NWAVES];   // {hi32 of winner value, winner oi}
    __shared__ float4 s_c[2][NWAVES];    // {x, y, z, lo32-as-float}
    __shared__ int    s_hist[4096];      // npoints <= 4096
    __shared__ int    s_perm[N_IN];      // sorted position -> original index
    __shared__ int    s_cnt[512];
    __shared__ int    s_off[512];
    __shared__ float  s_rmin[3][NWAVES];
    __shared__ float  s_rmax[3][NWAVES];

    f32x2  pcx[NPAIR], pcy[NPAIR], pcz[NPAIR];
    double md[PPT];
    float  th[PPT];
    int    oi[PPT];
    int    cell[PPT];

    // ---- setup pass 1: strided coalesced load; global bbox ----
    float mnx = 3.4e38f, mny = 3.4e38f, mnz = 3.4e38f;
    float mxx = -3.4e38f, mxy = -3.4e38f, mxz = -3.4e38f;
#pragma unroll
    for (int j = 0; j < PPT; ++j) {
        int p = j * NT + tid;
        const float* r = base + (size_t)p * stride;
        float x = r[0], y = r[1], z = r[2];
        pcx[j / 2][j & 1] = x; pcy[j / 2][j & 1] = y; pcz[j / 2][j & 1] = z;
        mnx = fminf(mnx, x); mny = fminf(mny, y); mnz = fminf(mnz, z);
        mxx = fmaxf(mxx, x); mxy = fmaxf(mxy, y); mxz = fmaxf(mxz, z);
    }
    mnx = wave_fmin64(mnx); mny = wave_fmin64(mny); mnz = wave_fmin64(mnz);
    mxx = wave_fmax64(mxx); mxy = wave_fmax64(mxy); mxz = wave_fmax64(mxz);
    if (lane == 63) {
        s_rmin[0][wv] = mnx; s_rmin[1][wv] = mny; s_rmin[2][wv] = mnz;
        s_rmax[0][wv] = mxx; s_rmax[1][wv] = mxy; s_rmax[2][wv] = mxz;
    }
    if (tid < 512) s_cnt[tid] = 0;
    __syncthreads();
    float lox = s_rmin[0][0], loy = s_rmin[1][0], loz = s_rmin[2][0];
    float hix = s_rmax[0][0], hiy = s_rmax[1][0], hiz = s_rmax[2][0];
    for (int w = 1; w < NWAVES; ++w) {
        lox = fminf(lox, s_rmin[0][w]); loy = fminf(loy, s_rmin[1][w]); loz = fminf(loz, s_rmin[2][w]);
        hix = fmaxf(hix, s_rmax[0][w]); hiy = fmaxf(hiy, s_rmax[1][w]); hiz = fmaxf(hiz, s_rmax[2][w]);
    }
    float exq = hix - lox, eyq = hiy - loy, ezq = hiz - loz;
    float ivx = (exq > 0.f) ? (8.0f / exq) : 0.f;
    float ivy = (eyq > 0.f) ? (8.0f / eyq) : 0.f;
    float ivz = (ezq > 0.f) ? (8.0f / ezq) : 0.f;

    // ---- cell ids + histogram ----
#pragma unroll
    for (int j = 0; j < PPT; ++j) {
        float x = pcx[j / 2][j & 1], y = pcy[j / 2][j & 1], z = pcz[j / 2][j & 1];
        int cx = min(7, max(0, (int)((x - lox) * ivx)));
        int cy = min(7, max(0, (int)((y - loy) * ivy)));
        int cz = min(7, max(0, (int)((z - loz) * ivz)));
        cell[j] = (cx << 6) | (cy << 3) | cz;
    }
#pragma unroll
    for (int j = 0; j < PPT; ++j) atomicAdd(&s_cnt[cell[j]], 1);
    __syncthreads();

    // ---- Hillis-Steele inclusive scan over 512 cells ----
    for (int off = 1; off < 512; off <<= 1) {
        int v = 0;
        if (tid < 512 && tid >= off) v = s_cnt[tid - off];
        __syncthreads();
        if (tid < 512) s_cnt[tid] += v;
        __syncthreads();
    }
    if (tid < 512) s_off[tid] = (tid == 0) ? 0 : s_cnt[tid - 1];
    __syncthreads();

    // ---- scatter permutation (orig index into sorted position) ----
#pragma unroll
    for (int j = 0; j < PPT; ++j) {
        int pos = atomicAdd(&s_off[cell[j]], 1);
        s_perm[pos] = j * NT + tid;
    }
    __syncthreads();

    // ---- gather: wave wv owns sorted range [wv*WPTS, (wv+1)*WPTS) ----
#pragma unroll
    for (int j = 0; j < PPT; ++j) {
        int spos = wv * WPTS + j * 64 + lane;
        int p = s_perm[spos];
        oi[j] = p;
        const float* r = base + (size_t)p * stride;
        pcx[j / 2][j & 1] = r[0]; pcy[j / 2][j & 1] = r[1]; pcz[j / 2][j & 1] = r[2];
    }
    // wave bbox of owned points
    float wlx = 3.4e38f, wly = 3.4e38f, wlz = 3.4e38f;
    float whx = -3.4e38f, why = -3.4e38f, whz = -3.4e38f;
#pragma unroll
    for (int j = 0; j < PPT; ++j) {
        wlx = fminf(wlx, pcx[j / 2][j & 1]); wly = fminf(wly, pcy[j / 2][j & 1]); wlz = fminf(wlz, pcz[j / 2][j & 1]);
        whx = fmaxf(whx, pcx[j / 2][j & 1]); why = fmaxf(why, pcy[j / 2][j & 1]); whz = fmaxf(whz, pcz[j / 2][j & 1]);
    }
    wlx = readlane_f32(wave_fmin64(wlx), 63); wly = readlane_f32(wave_fmin64(wly), 63);
    wlz = readlane_f32(wave_fmin64(wlz), 63);
    whx = readlane_f32(wave_fmax64(whx), 63); why = readlane_f32(wave_fmax64(why), 63);
    whz = readlane_f32(wave_fmax64(whz), 63);

    // ---- init: first selected point is ORIGINAL index 0 ----
    float q0x = base[0], q0y = base[1], q0z = base[2];
    if (tid == 0) s_hist[0] = 0;

    double bv = -1.0;
    int    bj = 0, boi = 0x7FFFFFFF;
    float  bx = 0.f, by = 0.f, bz = 0.f;
#pragma unroll
    for (int j = 0; j < PPT; ++j) {
        float x = pcx[j / 2][j & 1], y = pcy[j / 2][j & 1], z = pcz[j / 2][j & 1];
        md[j] = dist2d(x, y, z, (double)q0x, (double)q0y, (double)q0z);
        th[j] = __fmul_rn((float)md[j], 1.000004f);
        if (md[j] > bv || (md[j] == bv && oi[j] < boi)) {
            bv = md[j]; bj = j; boi = oi[j]; bx = x; by = y; bz = z;
        }
    }
    // stale-high bound on wave max th (th only decreases; refreshed on rescan)
    float tl = th[0];
#pragma unroll
    for (int j = 1; j < PPT; ++j) tl = fmaxf(tl, th[j]);
    float tmaxw = readlane_f32(wave_fmax64(tl), 63);

    // cached wave winner (wave-uniform after reduce_winner)
    unsigned w_hi = 0, w_lo = 0;
    int      w_i  = 0;
    float    w_x = 0.f, w_y = 0.f, w_z = 0.f;
    bool pub0 = false, pub1 = false;

    auto reduce_winner = [&]() {
        unsigned hi = (unsigned)__double2hiint(bv);
        unsigned lo = (unsigned)__double2loint(bv);
        unsigned maxhi = (unsigned)__builtin_amdgcn_readlane((int)wave_umax64(hi), 63);
        int wl = pick_lane(__ballot(hi == maxhi), lo, boi);
        w_hi = maxhi;
        w_lo = (unsigned)__builtin_amdgcn_readlane((int)lo, wl);
        w_i  = __builtin_amdgcn_readlane(boi, wl);
        w_x  = readlane_f32(bx, wl);
        w_y  = readlane_f32(by, wl);
        w_z  = readlane_f32(bz, wl);
        pub0 = false; pub1 = false;
    };
    reduce_winner();

    for (int i = 1; i < npoints; ++i) {
        const int par = i & 1;

        // ---- phase 1: publish cached winner (skip if buffer current) ----
        bool pub = par ? pub1 : pub0;
        if (!pub) {
            if (lane == 0) {
                s_pk[par][wv] = make_uint2(w_hi, (unsigned)w_i);
                s_c[par][wv]  = make_float4(w_x, w_y, w_z, __uint_as_float(w_lo));
            }
            if (par) pub1 = true; else pub0 = true;
        }
        __syncthreads();   // no outstanding vmem in-loop -> vmcnt drain free

        // ---- phase 2: reduce NWAVES partials; loads masked to lane<NWAVES ----
        unsigned phi = 0u, pidx = 0u;
        float pqx = 0.f, pqy = 0.f, pqz = 0.f, plo = 0.f;
        if (lane < NWAVES) {
            uint2  pk = s_pk[par][lane];
            float4 pc = s_c[par][lane];
            phi = pk.x; pidx = pk.y;
            pqx = pc.x; pqy = pc.y; pqz = pc.z; plo = pc.w;
        }
        unsigned v2 = phi;   // lanes >= NWAVES hold 0
        v2 = max(v2, dpp_u32_keep<0x111>(v2));
        v2 = max(v2, dpp_u32_keep<0x112>(v2));
        if constexpr (NWAVES >= 8)  v2 = max(v2, dpp_u32_keep<0x114>(v2));
        if constexpr (NWAVES >= 16) v2 = max(v2, dpp_u32_keep<0x118>(v2));
        unsigned ghi = (unsigned)__builtin_amdgcn_readlane((int)v2, NWAVES - 1);
        int wl2 = pick_lane(__ballot((lane < NWAVES) && (phi == ghi)),
                            (unsigned)__float_as_int(plo), (int)pidx);
        int best = __builtin_amdgcn_readlane((int)pidx, wl2);
        if (tid == 0) s_hist[i] = best;

        // winner coords via readlane (no dependent LDS read)
        const float qx = readlane_f32(pqx, wl2);
        const float qy = readlane_f32(pqy, wl2);
        const float qz = readlane_f32(pqz, wl2);

        // ---- wave-level conservative skip (bbox vs stale-high tmaxw) ----
        float cqx = fminf(fmaxf(qx, wlx), whx);
        float cqy = fminf(fmaxf(qy, wly), why);
        float cqz = fminf(fmaxf(qz, wlz), whz);
        float ddx = qx - cqx, ddy = qy - cqy, ddz = qz - cqz;
        float d2b = fmaf(ddx, ddx, fmaf(ddy, ddy, ddz * ddz));
        if (d2b > __fmul_rn(tmaxw, 1.00002f)) continue;   // provably no hit

        const double qx64 = (double)qx, qy64 = (double)qy, qz64 = (double)qz;

        // ---- packed branchless screen -> wave-uniform fire mask ----
        const f32x2 nqx = {-qx, -qx}, nqy = {-qy, -qy}, nqz = {-qz, -qz};
        int fmask = 0;
#pragma unroll
        for (int k = 0; k < NPAIR; ++k) {
            f32x2 dx = pk_add(pcx[k], nqx);
            f32x2 dy = pk_add(pcy[k], nqy);
            f32x2 dz = pk_add(pcz[k], nqz);
            f32x2 d  = pk_fma(dx, dx, pk_fma(dy, dy, pk_mul(dz, dz)));
            fmask |= (__any(d.x < th[2 * k])     ? (1 << (2 * k))     : 0);
            fmask |= (__any(d.y < th[2 * k + 1]) ? (1 << (2 * k + 1)) : 0);
        }

        if (fmask) {
            bool need = false;
#pragma unroll
            for (int j = 0; j < PPT; ++j) {
                if (fmask & (1 << j)) {
                    float x = pcx[j / 2][j & 1], y = pcy[j / 2][j & 1], z = pcz[j / 2][j & 1];
                    double d   = dist2d(x, y, z, qx64, qy64, qz64);
                    double old = md[j];
                    // stale iff the best slot itself decreased (d<old<=bv means
                    // no decrease can create a NEW tie at bv)
                    need = need | ((bj == j) & (d < old));
                    md[j] = fmin(old, d);
                    th[j] = __fmul_rn((float)md[j], 1.000004f);
                }
            }
            if (__any(need)) {
                bv = -1.0; bj = 0; boi = 0x7FFFFFFF;
#pragma unroll
                for (int j = 0; j < PPT; ++j) {
                    if (md[j] > bv || (md[j] == bv && oi[j] < boi)) {
                        bv = md[j]; bj = j; boi = oi[j];
                        bx = pcx[j / 2][j & 1]; by = pcy[j / 2][j & 1]; bz = pcz[j / 2][j & 1];
                    }
                }
                // refresh the wave th bound (exact current max)
                float t2 = th[0];
#pragma unroll
                for (int j = 1; j < PPT; ++j) t2 = fmaxf(t2, th[j]);
                tmaxw = readlane_f32(wave_fmax64(t2), 63);
                reduce_winner();
            }
        }
    }

    // coalesced bulk dump of the selected indices
    __syncthreads();
    for (int k = tid; k < npoints; k += NT) iout[k] = s_hist[k];
}

// ---------------------------------------------------------------------------
// Gather + 2-layer pointwise MLP + xyz/feat concat, one kernel per level.
// IDENT=true: identity gather (FPS nesting property -> idx == arange).
// ---------------------------------------------------------------------------
template <int CIN, int F, bool REPEAT, bool IDENT>
__global__ __launch_bounds__(256) void mlp_kernel(
    const float* __restrict__ pts, int stride, int n_in,
    const int* __restrict__ idx,
    const float* __restrict__ w1, const float* __restrict__ b1,
    const float* __restrict__ w2, const float* __restrict__ b2,
    float* __restrict__ out, int np)
{
    constexpr int P    = 256 / F;
    constexpr int CINS = REPEAT ? (CIN / 2) : CIN;  // stored input channels
    constexpr int LOGF = (F == 16) ? 4 : (F == 32) ? 5 : (F == 64) ? 6 : 7;

    __shared__ float xs[P][CINS];
    __shared__ float h[P][F];

    const int tid = threadIdx.x;
    const int pl  = tid >> LOGF;       // point within block
    const int c   = tid & (F - 1);     // output channel
    const int b   = blockIdx.y;
    const int pid = blockIdx.x * P + pl;

    const int id = IDENT ? pid : idx[(size_t)b * np + pid];
    const float* row = pts + ((size_t)b * n_in + id) * stride;

    if (c < CINS) xs[pl][c] = row[c];
    __syncthreads();

    float acc = b1[c];
#pragma unroll
    for (int k = 0; k < CIN; ++k) {
        const int xk = REPEAT ? (k % 3) : k;
        acc = fmaf(xs[pl][xk], w1[k * F + c], acc);
    }
    h[pl][c] = fmaxf(acc, 0.0f);
    __syncthreads();

    float acc2 = b2[c];
#pragma unroll
    for (int f = 0; f < F; ++f)
        acc2 = fmaf(h[pl][f], w2[f * F + c], acc2);

    float res = (c < 3) ? xs[pl][c] : acc2;
    out[((size_t)b * np + pid) * (size_t)F + c] = res;
}

// ---------------------------------------------------------------------------
// Launch. Only level-1 FPS is computed; levels 2-4 are identity gathers.
// ---------------------------------------------------------------------------
extern "C" void kernel_launch(void* const* d_in, const int* in_sizes, int n_in_cnt,
                              void* d_out, int out_size, void* d_ws, size_t ws_size,
                              hipStream_t stream) {
    const float* scene = (const float*)d_in[0];
    const float* w1_1 = (const float*)d_in[1];
    const float* b1_1 = (const float*)d_in[2];
    const float* w2_1 = (const float*)d_in[3];
    const float* b2_1 = (const float*)d_in[4];
    const float* w1_2 = (const float*)d_in[5];
    const float* b1_2 = (const float*)d_in[6];
    const float* w2_2 = (const float*)d_in[7];
    const float* b2_2 = (const float*)d_in[8];
    const float* w1_3 = (const float*)d_in[9];
    const float* b1_3 = (const float*)d_in[10];
    const float* w2_3 = (const float*)d_in[11];
    const float* b2_3 = (const float*)d_in[12];
    const float* w1_4 = (const float*)d_in[13];
    const float* b1_4 = (const float*)d_in[14];
    const float* w2_4 = (const float*)d_in[15];
    const float* b2_4 = (const float*)d_in[16];

    float* out  = (float*)d_out;
    float* out1 = out;                 // [8][4096][16]
    float* out2 = out + 524288;        // [8][2048][32]
    float* out3 = out + 1048576;       // [8][1024][64]
    float* out4 = out + 1572864;       // [8][512][128]

    int* idx1 = (int*)d_ws;            // 8*4096 (only level-1 indices needed)

    const int B = 8;

    // Level 1: N=8192 -> 4096, cin=6 (repeat), F=16
    fps_kernel<8, 1024><<<B, 1024, 0, stream>>>(scene, 3, 4096, idx1);
    mlp_kernel<6, 16, true, false><<<dim3(256, B), 256, 0, stream>>>(
        scene, 3, 8192, idx1, w1_1, b1_1, w2_1, b2_1, out1, 4096);

    // Level 2: 4096 -> 2048, cin=16, F=32   (identity gather, no FPS)
    mlp_kernel<16, 32, false, true><<<dim3(256, B), 256, 0, stream>>>(
        out1, 16, 4096, nullptr, w1_2, b1_2, w2_2, b2_2, out2, 2048);

    // Level 3: 2048 -> 1024, cin=32, F=64   (identity gather, no FPS)
    mlp_kernel<32, 64, false, true><<<dim3(256, B), 256, 0, stream>>>(
        out2, 32, 2048, nullptr, w1_3, b1_3, w2_3, b2_3, out3, 1024);

    // Level 4: 1024 -> 512, cin=64, F=128   (identity gather, no FPS)
    mlp_kernel<64, 128, false, true><<<dim3(256, B), 256, 0, stream>>>(
        out3, 64, 1024, nullptr, w1_4, b1_4, w2_4, b2_4, out4, 512);
}

// Round 11
// 5089.123 us; speedup vs baseline: 3.0083x; 1.1651x over previous
//
#include <hip/hip_runtime.h>

typedef float f32x2 __attribute__((ext_vector_type(2)));

// ---------------------------------------------------------------------------
// VOP3P packed f32 (2 f32 ops per instruction per lane). Same IEEE f32 RN
// rounding per element as the scalar ops they replace.
// ---------------------------------------------------------------------------
__device__ __forceinline__ f32x2 pk_add(f32x2 a, f32x2 b) {
    f32x2 d; asm("v_pk_add_f32 %0, %1, %2" : "=v"(d) : "v"(a), "v"(b)); return d;
}
__device__ __forceinline__ f32x2 pk_mul(f32x2 a, f32x2 b) {
    f32x2 d; asm("v_pk_mul_f32 %0, %1, %2" : "=v"(d) : "v"(a), "v"(b)); return d;
}
__device__ __forceinline__ f32x2 pk_fma(f32x2 a, f32x2 b, f32x2 c) {
    f32x2 d; asm("v_pk_fma_f32 %0, %1, %2, %3" : "=v"(d) : "v"(a), "v"(b), "v"(c)); return d;
}

// ---------------------------------------------------------------------------
// Strict f64 squared distance matching numpy float64:
//   d = ((dx*dx + dy*dy) + dz*dz), every op individually rounded, no FMA.
// ---------------------------------------------------------------------------
__device__ __forceinline__ double dist2d(float x, float y, float z,
                                         double px, double py, double pz) {
    double dx = __dsub_rn((double)x, px);
    double dy = __dsub_rn((double)y, py);
    double dz = __dsub_rn((double)z, pz);
    double a  = __dmul_rn(dx, dx);
    double b  = __dmul_rn(dy, dy);
    double c  = __dmul_rn(dz, dz);
    return __dadd_rn(__dadd_rn(a, b), c);
}

// DPP move; lanes with invalid source keep their own value (bound_ctrl=false).
template <int CTRL>
__device__ __forceinline__ unsigned dpp_u32_keep(unsigned v) {
    return (unsigned)__builtin_amdgcn_update_dpp((int)v, (int)v, CTRL, 0xF, 0xF, false);
}

// After this, lane 63 holds umax over all 64 lanes.
__device__ __forceinline__ unsigned wave_umax64(unsigned v) {
    v = max(v, dpp_u32_keep<0x111>(v));  // row_shr:1
    v = max(v, dpp_u32_keep<0x112>(v));  // row_shr:2
    v = max(v, dpp_u32_keep<0x114>(v));  // row_shr:4
    v = max(v, dpp_u32_keep<0x118>(v));  // row_shr:8
    v = max(v, dpp_u32_keep<0x142>(v));  // row_bcast:15
    v = max(v, dpp_u32_keep<0x143>(v));  // row_bcast:31
    return v;
}

__device__ __forceinline__ float readlane_f32(float v, int l) {
    return __int_as_float(__builtin_amdgcn_readlane(__float_as_int(v), l));
}

// ---------------------------------------------------------------------------
// FPS. One block per batch. Point p = j*NT + tid, j < PPT, n_in = PPT*NT.
//
// THE MEASURED CHAMPION (R4: fps 4986us, e2e 5095us, VGPR 64). Reverted to
// after six structural variants each regressed for an identified reason:
//   - speculative 2-picks/convoy (+9%): runner-up is almost always inside
//     p1's screen radius -> happy-rate ~0, steady top-2 overhead pure cost.
//   - lazy top-2 bookkeeping (+2%): added issue without shortening wall.
//   - NT=512 (+27%): latency term needs 4 waves/SIMD to partially overlap.
//   - 2 batches/block (+207%): state doesn't fit 128 VGPR -> scratch spills.
//   - spatial sort + bbox skip (+17%): barrier makespan = MAX over waves;
//     clustering CONCENTRATES the update on 1-2 waves while 14 idle.
//     Random point assignment is the optimal update load-balancer.
//
// Exactness: md is f64, bit-matching numpy float64 (dist2d). md >= 0, and for
// non-negative IEEE doubles value order == integer order of (hi32, lo32), so
// all max machinery runs on u32 hi-words (v_max_u32 DPP); exact hi-ties fall
// to a rare readlane slow path resolving (lo desc, idx asc). argmax
// tie-break = global min index (numpy argmax), via keep-first in-lane scans.
//
// Issue-count machinery:
//   - cached wave winner: the 64-lane DPP reduce + ballot + readlane extract
//     runs ONLY after a rescan (reduce_winner); steady-state phase 1 is just
//     two masked LDS writes, skipped when the parity buffer is current
//     (pub0/pub1 flags). Safe: the selected point always fires its own
//     wave's rescan (its own slot takes d=0 < md with bj==j), so a stale
//     cached winner is impossible.
//   - rescan-skip: updates only DECREASE md; keep-first invariant => all
//     j < bj have md[j] < bv strictly, so no new smaller-index tie can form.
//     The lane state is stale iff slot bj itself took d < old. Gate the
//     whole rescan+reduce on __any((j==bj) && (d<old)).
//   - phase 2: lane l<NWAVES loads partial l's {hi,idx} AND {coords,lo}
//     together; winner coords come from readlanes, not a dependent LDS read.
//   - screen: v_pk_* packed f32, per-element rounding identical to scalar;
//     margin 1.000004 >> 3-ulp fma error => screened-out slots provably
//     unchanged; md stays bit-exact.
//   - ZERO global memory ops in the serial loop (LDS history, bulk dump).
//
// Hang/poison safety: barriers at top-level with block-uniform trip count;
// tie slow-path loops iterate a strictly-shrinking ballot mask (<=64 iters);
// all in-loop indexing is LDS with construction-bounded indices; 'best' is
// never used as a memory offset, only stored; per-lane arrays use
// compile-time indices only.
//
// Only level-1 FPS runs. FPS is nested: FPS on the ordered output of a
// previous FPS selects indices 0,1,2,... bit-exactly (subset-max argument;
// selected points have running dist 0; argmax tie-break = first occurrence).
// So idx2/3/4 are arange() -> identity gathers in the MLP levels.
// ---------------------------------------------------------------------------
template <int PPT, int NT>
__global__ __launch_bounds__(NT, 4) void fps_kernel(
    const float* __restrict__ pts,  // [B][n_in][stride], xyz at channels 0..2
    int stride, int npoints,
    int* __restrict__ idx_out)      // [B][npoints]
{
    constexpr int NWAVES = NT / 64;
    constexpr int N_IN   = PPT * NT;
    constexpr int NPAIR  = PPT / 2;
    constexpr int LOGNT  = (NT == 1024) ? 10 : (NT == 512) ? 9 : 8;

    const int batch = blockIdx.x;
    const int tid   = threadIdx.x;
    const int lane  = tid & 63;
    const int wv    = tid >> 6;

    const float* base = pts + (size_t)batch * N_IN * stride;
    int* iout = idx_out + (size_t)batch * npoints;

    __shared__ uint2  s_pk[2][NWAVES];   // {hi32 of winner value, winner idx}
    __shared__ float4 s_c[2][NWAVES];    // {x, y, z, lo32-as-float}
    __shared__ int    s_hist[4096];      // npoints <= 4096

    f32x2  pcx[NPAIR], pcy[NPAIR], pcz[NPAIR];
    double md[PPT];
    float  th[PPT];

#pragma unroll
    for (int k = 0; k < NPAIR; ++k) {
        int p0 = (2 * k) * NT + tid;
        int p1 = (2 * k + 1) * NT + tid;
        const float* r0 = base + (size_t)p0 * stride;
        const float* r1 = base + (size_t)p1 * stride;
        pcx[k] = f32x2{r0[0], r1[0]};
        pcy[k] = f32x2{r0[1], r1[1]};
        pcz[k] = f32x2{r0[2], r1[2]};
    }

    // first selected point is index 0
    float q0x = base[0], q0y = base[1], q0z = base[2];
    if (tid == 0) s_hist[0] = 0;

    // per-lane argmax state: value (f64), slot, coords. keep-first scan.
    double bv = -1.0;
    int    bj = 0;
    float  bx = 0.f, by = 0.f, bz = 0.f;
#pragma unroll
    for (int j = 0; j < PPT; ++j) {
        float x = pcx[j / 2][j & 1], y = pcy[j / 2][j & 1], z = pcz[j / 2][j & 1];
        md[j] = dist2d(x, y, z, (double)q0x, (double)q0y, (double)q0z);
        th[j] = __fmul_rn((float)md[j], 1.000004f);
        if (md[j] > bv) { bv = md[j]; bj = j; bx = x; by = y; bz = z; }
    }

    // cached wave winner (wave-uniform after reduce_winner)
    unsigned w_hi = 0, w_lo = 0;
    int      w_i  = 0;
    float    w_x = 0.f, w_y = 0.f, w_z = 0.f;
    bool pub0 = false, pub1 = false;

    auto reduce_winner = [&]() {
        unsigned hi = (unsigned)__double2hiint(bv);
        unsigned lo = (unsigned)__double2loint(bv);
        int      bi = (bj << LOGNT) + tid;
        unsigned maxhi = (unsigned)__builtin_amdgcn_readlane((int)wave_umax64(hi), 63);
        unsigned long long cm = __ballot(hi == maxhi);
        int wl;
        if (__popcll(cm) == 1) {
            wl = __ffsll(cm) - 1;
        } else {  // exact hi tie: resolve (lo desc, idx asc). rare.
            unsigned bl = 0; int bidx = 0x7FFFFFFF; int ml = -1;
            unsigned long long t2 = cm;
            while (t2) {
                int l = __ffsll(t2) - 1;
                unsigned lol = (unsigned)__builtin_amdgcn_readlane((int)lo, l);
                int      il  = __builtin_amdgcn_readlane(bi, l);
                if (ml < 0 || lol > bl || (lol == bl && il < bidx)) {
                    bl = lol; bidx = il; ml = l;
                }
                t2 &= t2 - 1;
            }
            wl = ml;
        }
        w_hi = maxhi;
        w_lo = (unsigned)__builtin_amdgcn_readlane((int)lo, wl);
        w_i  = __builtin_amdgcn_readlane(bi, wl);
        w_x  = readlane_f32(bx, wl);
        w_y  = readlane_f32(by, wl);
        w_z  = readlane_f32(bz, wl);
        pub0 = false; pub1 = false;
    };
    reduce_winner();

    for (int i = 1; i < npoints; ++i) {
        const int par = i & 1;

        // ---- phase 1: publish cached winner (skip if buffer current) ----
        bool pub = par ? pub1 : pub0;
        if (!pub) {
            if (lane == 0) {
                s_pk[par][wv] = make_uint2(w_hi, (unsigned)w_i);
                s_c[par][wv]  = make_float4(w_x, w_y, w_z, __uint_as_float(w_lo));
            }
            if (par) pub1 = true; else pub0 = true;
        }
        __syncthreads();   // no outstanding vmem in-loop -> vmcnt drain free

        // ---- phase 2: reduce NWAVES partials (redundant per wave) ----
        const int sl = lane & (NWAVES - 1);
        uint2  pk = s_pk[par][sl];
        float4 pc = s_c[par][sl];
        unsigned v2 = (lane < NWAVES) ? pk.x : 0u;
        v2 = max(v2, dpp_u32_keep<0x111>(v2));
        v2 = max(v2, dpp_u32_keep<0x112>(v2));
        if constexpr (NWAVES >= 8)  v2 = max(v2, dpp_u32_keep<0x114>(v2));
        if constexpr (NWAVES >= 16) v2 = max(v2, dpp_u32_keep<0x118>(v2));
        unsigned ghi = (unsigned)__builtin_amdgcn_readlane((int)v2, NWAVES - 1);
        unsigned long long c2 = __ballot((lane < NWAVES) && (pk.x == ghi));
        int wl2;
        if (__popcll(c2) == 1) {
            wl2 = __ffsll(c2) - 1;
        } else {  // exact hi tie across waves: (lo desc, idx asc). rare.
            unsigned bl = 0; int bidx = 0x7FFFFFFF; int ml = -1;
            unsigned long long t2 = c2;
            while (t2) {
                int l = __ffsll(t2) - 1;
                unsigned lol = (unsigned)__builtin_amdgcn_readlane(__float_as_int(pc.w), l);
                int      il  = __builtin_amdgcn_readlane((int)pk.y, l);
                if (ml < 0 || lol > bl || (lol == bl && il < bidx)) {
                    bl = lol; bidx = il; ml = l;
                }
                t2 &= t2 - 1;
            }
            wl2 = ml;
        }
        int best = __builtin_amdgcn_readlane((int)pk.y, wl2);
        if (tid == 0) s_hist[i] = best;

        // winner coords via readlane (no dependent LDS read)
        const float qx = readlane_f32(pc.x, wl2);
        const float qy = readlane_f32(pc.y, wl2);
        const float qz = readlane_f32(pc.z, wl2);
        const double qx64 = (double)qx, qy64 = (double)qy, qz64 = (double)qz;

        // ---- packed branchless screen -> wave-uniform fire mask ----
        const f32x2 nqx = {-qx, -qx}, nqy = {-qy, -qy}, nqz = {-qz, -qz};
        int fmask = 0;
#pragma unroll
        for (int k = 0; k < NPAIR; ++k) {
            f32x2 dx = pk_add(pcx[k], nqx);
            f32x2 dy = pk_add(pcy[k], nqy);
            f32x2 dz = pk_add(pcz[k], nqz);
            f32x2 d  = pk_fma(dx, dx, pk_fma(dy, dy, pk_mul(dz, dz)));
            fmask |= (__any(d.x < th[2 * k])     ? (1 << (2 * k))     : 0);
            fmask |= (__any(d.y < th[2 * k + 1]) ? (1 << (2 * k + 1)) : 0);
        }

        if (fmask) {
            bool need = false;
#pragma unroll
            for (int j = 0; j < PPT; ++j) {
                if (fmask & (1 << j)) {
                    float x = pcx[j / 2][j & 1], y = pcy[j / 2][j & 1], z = pcz[j / 2][j & 1];
                    double d   = dist2d(x, y, z, qx64, qy64, qz64);
                    double old = md[j];
                    // stale iff the best slot itself decreased (see proof above)
                    need = need | ((bj == j) & (d < old));
                    md[j] = fmin(old, d);
                    th[j] = __fmul_rn((float)md[j], 1.000004f);
                }
            }
            if (__any(need)) {
                bv = -1.0; bj = 0;
#pragma unroll
                for (int j = 0; j < PPT; ++j) {
                    if (md[j] > bv) {
                        bv = md[j]; bj = j;
                        bx = pcx[j / 2][j & 1]; by = pcy[j / 2][j & 1]; bz = pcz[j / 2][j & 1];
                    }
                }
                reduce_winner();
            }
        }
    }

    // coalesced bulk dump of the selected indices
    __syncthreads();
    for (int k = tid; k < npoints; k += NT) iout[k] = s_hist[k];
}

// ---------------------------------------------------------------------------
// Gather + 2-layer pointwise MLP + xyz/feat concat, one kernel per level.
// IDENT=true: identity gather (FPS nesting property -> idx == arange).
// ---------------------------------------------------------------------------
template <int CIN, int F, bool REPEAT, bool IDENT>
__global__ __launch_bounds__(256) void mlp_kernel(
    const float* __restrict__ pts, int stride, int n_in,
    const int* __restrict__ idx,
    const float* __restrict__ w1, const float* __restrict__ b1,
    const float* __restrict__ w2, const float* __restrict__ b2,
    float* __restrict__ out, int np)
{
    constexpr int P    = 256 / F;
    constexpr int CINS = REPEAT ? (CIN / 2) : CIN;  // stored input channels
    constexpr int LOGF = (F == 16) ? 4 : (F == 32) ? 5 : (F == 64) ? 6 : 7;

    __shared__ float xs[P][CINS];
    __shared__ float h[P][F];

    const int tid = threadIdx.x;
    const int pl  = tid >> LOGF;       // point within block
    const int c   = tid & (F - 1);     // output channel
    const int b   = blockIdx.y;
    const int pid = blockIdx.x * P + pl;

    const int id = IDENT ? pid : idx[(size_t)b * np + pid];
    const float* row = pts + ((size_t)b * n_in + id) * stride;

    if (c < CINS) xs[pl][c] = row[c];
    __syncthreads();

    float acc = b1[c];
#pragma unroll
    for (int k = 0; k < CIN; ++k) {
        const int xk = REPEAT ? (k % 3) : k;
        acc = fmaf(xs[pl][xk], w1[k * F + c], acc);
    }
    h[pl][c] = fmaxf(acc, 0.0f);
    __syncthreads();

    float acc2 = b2[c];
#pragma unroll
    for (int f = 0; f < F; ++f)
        acc2 = fmaf(h[pl][f], w2[f * F + c], acc2);

    float res = (c < 3) ? xs[pl][c] : acc2;
    out[((size_t)b * np + pid) * (size_t)F + c] = res;
}

// ---------------------------------------------------------------------------
// Launch. Only level-1 FPS is computed; levels 2-4 are identity gathers.
// ---------------------------------------------------------------------------
extern "C" void kernel_launch(void* const* d_in, const int* in_sizes, int n_in_cnt,
                              void* d_out, int out_size, void* d_ws, size_t ws_size,
                              hipStream_t stream) {
    const float* scene = (const float*)d_in[0];
    const float* w1_1 = (const float*)d_in[1];
    const float* b1_1 = (const float*)d_in[2];
    const float* w2_1 = (const float*)d_in[3];
    const float* b2_1 = (const float*)d_in[4];
    const float* w1_2 = (const float*)d_in[5];
    const float* b1_2 = (const float*)d_in[6];
    const float* w2_2 = (const float*)d_in[7];
    const float* b2_2 = (const float*)d_in[8];
    const float* w1_3 = (const float*)d_in[9];
    const float* b1_3 = (const float*)d_in[10];
    const float* w2_3 = (const float*)d_in[11];
    const float* b2_3 = (const float*)d_in[12];
    const float* w1_4 = (const float*)d_in[13];
    const float* b1_4 = (const float*)d_in[14];
    const float* w2_4 = (const float*)d_in[15];
    const float* b2_4 = (const float*)d_in[16];

    float* out  = (float*)d_out;
    float* out1 = out;                 // [8][4096][16]
    float* out2 = out + 524288;        // [8][2048][32]
    float* out3 = out + 1048576;       // [8][1024][64]
    float* out4 = out + 1572864;       // [8][512][128]

    int* idx1 = (int*)d_ws;            // 8*4096 (only level-1 indices needed)

    const int B = 8;

    // Level 1: N=8192 -> 4096, cin=6 (repeat), F=16
    fps_kernel<8, 1024><<<B, 1024, 0, stream>>>(scene, 3, 4096, idx1);
    mlp_kernel<6, 16, true, false><<<dim3(256, B), 256, 0, stream>>>(
        scene, 3, 8192, idx1, w1_1, b1_1, w2_1, b2_1, out1, 4096);

    // Level 2: 4096 -> 2048, cin=16, F=32   (identity gather, no FPS)
    mlp_kernel<16, 32, false, true><<<dim3(256, B), 256, 0, stream>>>(
        out1, 16, 4096, nullptr, w1_2, b1_2, w2_2, b2_2, out2, 2048);

    // Level 3: 2048 -> 1024, cin=32, F=64   (identity gather, no FPS)
    mlp_kernel<32, 64, false, true><<<dim3(256, B), 256, 0, stream>>>(
        out2, 32, 2048, nullptr, w1_3, b1_3, w2_3, b2_3, out3, 1024);

    // Level 4: 1024 -> 512, cin=64, F=128   (identity gather, no FPS)
    mlp_kernel<64, 128, false, true><<<dim3(256, B), 256, 0, stream>>>(
        out3, 64, 1024, nullptr, w1_4, b1_4, w2_4, b2_4, out4, 512);
}